// Round 1
// baseline (611.596 us; speedup 1.0000x reference)
//
#include <hip/hip_runtime.h>
#include <hip/hip_bf16.h>

#define B_ 32
#define T_ 1000
#define H_ 512
#define V_ 2048
#define L_ 100
#define M_ (B_*T_)          // 32000 rows
#define GSTRIDE 104         // p_ext row stride (floats): [0]=blank, [2+l]=label l
#define LOG2E 1.4426950408889634f
#define LSE_SHIFT 48.0f

typedef __attribute__((ext_vector_type(8))) short bf16x8;
typedef __attribute__((ext_vector_type(4))) float f32x4;

__device__ __forceinline__ unsigned short f2bf(float x) {
    unsigned int u; __builtin_memcpy(&u, &x, 4);
    unsigned int r = (u + 0x7fffu + ((u >> 16) & 1u)) >> 16;   // RNE
    return (unsigned short)r;
}

// ---------------------------------------------------------------------------
// Kernel 0: zero out + Srow, convert eouts/W fp32 -> bf16 into ws
// ---------------------------------------------------------------------------
__global__ __launch_bounds__(256) void prep_kernel(
        const float* __restrict__ eouts, const float* __restrict__ W,
        unsigned short* __restrict__ eb, unsigned short* __restrict__ wb,
        float* __restrict__ Srow, float* __restrict__ out)
{
    const int E4 = M_*H_/4;      // 4,096,000
    const int W4 = V_*H_/4;      //   262,144
    const int S4 = M_/4;         //     8,000
    int idx = blockIdx.x*256 + threadIdx.x;
    if (idx == 0) out[0] = 0.f;
    if (idx < E4) {
        float4 v = ((const float4*)eouts)[idx];
        ushort4 o; o.x=f2bf(v.x); o.y=f2bf(v.y); o.z=f2bf(v.z); o.w=f2bf(v.w);
        ((ushort4*)eb)[idx] = o;
    } else if (idx < E4 + W4) {
        int j = idx - E4;
        float4 v = ((const float4*)W)[j];
        ushort4 o; o.x=f2bf(v.x); o.y=f2bf(v.y); o.z=f2bf(v.z); o.w=f2bf(v.w);
        ((ushort4*)wb)[j] = o;
    } else if (idx < E4 + W4 + S4) {
        int j = idx - E4 - W4;
        ((float4*)Srow)[j] = make_float4(0.f,0.f,0.f,0.f);
    }
}

// ---------------------------------------------------------------------------
// Kernel 1: bf16 MFMA GEMM (logits = eouts @ W^T + b) fused with row-wise
// sum of 2^(logit*log2e - 48); Srow accumulated via atomics.
// Tile: 64(M) x 256(N), K-chunk 64. Block 256 thr = 4 waves, wave owns 64 N.
// ---------------------------------------------------------------------------
__global__ __launch_bounds__(256) void gemm_lse_kernel(
        const unsigned short* __restrict__ eb, const unsigned short* __restrict__ wb,
        const float* __restrict__ bias, float* __restrict__ Srow)
{
    __shared__ __align__(16) unsigned short As[64*72];    // pad 64->72 bf16
    __shared__ __align__(16) unsigned short Bs[256*72];
    __shared__ float rs[64];
    const int tid  = threadIdx.x;
    const int nbase = blockIdx.x * 256;
    const int mbase = blockIdx.y * 64;
    const int wid  = tid >> 6;
    const int lane = tid & 63;
    const int m    = lane & 15;
    const int q    = lane >> 4;
    if (tid < 64) rs[tid] = 0.f;

    f32x4 acc[4][4];
    #pragma unroll
    for (int i=0;i<4;i++)
        #pragma unroll
        for (int j=0;j<4;j++) acc[i][j] = (f32x4){0.f,0.f,0.f,0.f};

    for (int kc = 0; kc < 8; ++kc) {
        __syncthreads();
        #pragma unroll
        for (int i = 0; i < 2; ++i) {                 // stage A 64x64
            int c = tid + i*256;
            int r = c >> 3, k8 = c & 7;
            uint4 v = *(const uint4*)(eb + (size_t)(mbase + r)*H_ + kc*64 + k8*8);
            *(uint4*)(As + r*72 + k8*8) = v;
        }
        #pragma unroll
        for (int i = 0; i < 8; ++i) {                 // stage B 256x64
            int c = tid + i*256;
            int r = c >> 3, k8 = c & 7;
            uint4 v = *(const uint4*)(wb + (size_t)(nbase + r)*H_ + kc*64 + k8*8);
            *(uint4*)(Bs + r*72 + k8*8) = v;
        }
        __syncthreads();
        #pragma unroll
        for (int kk = 0; kk < 2; ++kk) {
            bf16x8 af[4], bfg[4];
            #pragma unroll
            for (int mi=0;mi<4;mi++)
                af[mi] = *(const bf16x8*)(As + (mi*16 + m)*72 + kk*32 + q*8);
            #pragma unroll
            for (int ni=0;ni<4;ni++)
                bfg[ni] = *(const bf16x8*)(Bs + (wid*64 + ni*16 + m)*72 + kk*32 + q*8);
            #pragma unroll
            for (int mi=0;mi<4;mi++)
                #pragma unroll
                for (int ni=0;ni<4;ni++)
                    acc[mi][ni] = __builtin_amdgcn_mfma_f32_16x16x32_bf16(
                        af[mi], bfg[ni], acc[mi][ni], 0, 0, 0);
        }
    }

    // epilogue: exp2 + row reduction. C/D layout: col=lane&15, row=q*4+reg.
    float bv[4];
    #pragma unroll
    for (int ni=0;ni<4;ni++) bv[ni] = bias[nbase + wid*64 + ni*16 + m];
    #pragma unroll
    for (int mi=0;mi<4;mi++) {
        #pragma unroll
        for (int r=0;r<4;r++) {
            float s = 0.f;
            #pragma unroll
            for (int ni=0;ni<4;ni++) {
                float z2 = (acc[mi][ni][r] + bv[ni]) * LOG2E;
                s += exp2f(z2 - LSE_SHIFT);
            }
            s += __shfl_xor(s, 1);
            s += __shfl_xor(s, 2);
            s += __shfl_xor(s, 4);
            s += __shfl_xor(s, 8);
            if (m == 0) atomicAdd(&rs[mi*16 + q*4 + r], s);
        }
    }
    __syncthreads();
    if (tid < 64) atomicAdd(&Srow[mbase + tid], rs[tid]);
}

// ---------------------------------------------------------------------------
// Kernel 2: gather ext-label probs. p = 2^(z2 - (48 + log2(Srow))).
// Block = (16 t) x (101 labels via 16 groups). fp32 dots of length 512.
// ---------------------------------------------------------------------------
__global__ __launch_bounds__(256) void gather_kernel(
        const float* __restrict__ eouts, const float* __restrict__ W,
        const float* __restrict__ bias, const int* __restrict__ ys,
        const float* __restrict__ Srow, float* __restrict__ g)
{
    __shared__ __align__(16) float es[16*129*4];   // float4[16][129] padded
    __shared__ int   ys_s[L_];
    __shared__ float lse_s[16];
    const int tid = threadIdx.x;
    const int b   = blockIdx.y;
    const int t0  = blockIdx.x * 16;

    #pragma unroll
    for (int i = 0; i < 8; ++i) {
        int c = tid + i*256;              // float4 index 0..2047
        int r = c >> 7, h4 = c & 127;
        int t = min(t0 + r, T_-1);
        float4 v = *(const float4*)(eouts + (size_t)(b*T_ + t)*H_ + h4*4);
        *(float4*)(es + (r*129 + h4)*4) = v;
    }
    if (tid < L_) ys_s[tid] = ys[b*L_ + tid];
    if (tid < 16) {
        int t = min(t0 + tid, T_-1);
        lse_s[tid] = LSE_SHIFT + log2f(Srow[b*T_ + t]);
    }
    __syncthreads();

    const int tl = tid & 15;
    const int li = tid >> 4;
    const int t  = t0 + tl;
    const float4* er = (const float4*)(es + tl*129*4);
    for (int lab = li; lab < L_+1; lab += 16) {
        int v = (lab == 0) ? 0 : ys_s[lab-1];
        const float4* wr = (const float4*)(W + (size_t)v*H_);
        float s0=0.f,s1=0.f,s2=0.f,s3=0.f;
        #pragma unroll 8
        for (int h4 = 0; h4 < 128; ++h4) {
            float4 e = er[h4];
            float4 w = wr[h4];
            s0 += e.x*w.x; s1 += e.y*w.y; s2 += e.z*w.z; s3 += e.w*w.w;
        }
        float z2 = (((s0+s1)+(s2+s3)) + bias[v]) * LOG2E;
        float p = exp2f(z2 - lse_s[tl]);
        if (t < T_) g[(size_t)(b*T_ + t)*GSTRIDE + (lab==0 ? 0 : lab+1)] = p;
    }
}

// ---------------------------------------------------------------------------
// Kernel 3: CTC forward DP, linear domain with periodic max-renorm.
// One wave per batch element; lane owns states 4*lane..4*lane+3.
// ---------------------------------------------------------------------------
__global__ __launch_bounds__(64) void ctc_dp_kernel(
        const float* __restrict__ g, const int* __restrict__ ys,
        const int* __restrict__ elens, const int* __restrict__ ylens,
        float* __restrict__ out)
{
    const int b    = blockIdx.x;
    const int lane = threadIdx.x;
    const float* gb = g + (size_t)b * T_ * GSTRIDE;
    const int ylen = ylens[b];
    const int elen = elens[b];
    const int Sv   = 2*ylen + 1;
    const int s0   = 4*lane;
    const float msk0 = (s0   < Sv) ? 1.f : 0.f;
    const float msk1 = (s0+1 < Sv) ? 1.f : 0.f;
    const float msk2 = (s0+2 < Sv) ? 1.f : 0.f;
    const float msk3 = (s0+3 < Sv) ? 1.f : 0.f;
    const int l0 = 2*lane, l1 = 2*lane + 1;
    int i0 = min(max(l0,1), L_-1);
    int i1 = min(l1, L_-1);
    float sk1 = (l0 >= 1 && l0 < L_ && ys[b*L_+i0] != ys[b*L_+i0-1]) ? 1.f : 0.f;
    float sk3 = (l1 < L_        && ys[b*L_+i1] != ys[b*L_+i1-1]) ? 1.f : 0.f;
    const bool ldok = (lane < 51);

    float pb0  = gb[0];
    float2 pl0 = ldok ? *(const float2*)(gb + 2 + 2*lane) : make_float2(0.f,0.f);
    float a0 = (lane==0) ? pb0   : 0.f;
    float a1 = (lane==0) ? pl0.x : 0.f;
    float a2 = 0.f, a3 = 0.f;
    float C2 = 0.f;   // accumulated log2 of renorm scales (wave-uniform)

    float pbA[8]; float2 plA[8];
    #pragma unroll
    for (int j=0;j<8;++j) {
        int tt = min(1+j, T_-1);
        pbA[j] = gb[tt*GSTRIDE];
        plA[j] = ldok ? *(const float2*)(gb + tt*GSTRIDE + 2 + 2*lane) : make_float2(0.f,0.f);
    }

    for (int tb = 1; tb < elen; tb += 8) {
        float pbB[8]; float2 plB[8];
        #pragma unroll
        for (int j=0;j<8;++j) {                       // prefetch next chunk
            int tt = min(tb+8+j, T_-1);
            pbB[j] = gb[tt*GSTRIDE];
            plB[j] = ldok ? *(const float2*)(gb + tt*GSTRIDE + 2 + 2*lane) : make_float2(0.f,0.f);
        }
        #pragma unroll
        for (int j=0;j<8;++j) {
            int t = tb + j;
            if (t < elen) {                           // wave-uniform guard
                float um1 = __shfl_up(a3, 1);         // prev lane state s0-1
                if (lane == 0) um1 = 0.f;
                float n0 = a0 + um1;
                float n1 = a1 + a0 + sk1*um1;
                float n2 = a2 + a1;
                float n3 = a3 + a2 + sk3*a1;
                a0 = n0 * pbA[j]   * msk0;
                a1 = n1 * plA[j].x * msk1;
                a2 = n2 * pbA[j]   * msk2;
                a3 = n3 * plA[j].y * msk3;
            }
            if ((j & 3) == 3) {                       // renorm every 4 steps
                float mm = fmaxf(fmaxf(a0,a1), fmaxf(a2,a3));
                mm = fmaxf(mm, __shfl_xor(mm, 1));
                mm = fmaxf(mm, __shfl_xor(mm, 2));
                mm = fmaxf(mm, __shfl_xor(mm, 4));
                mm = fmaxf(mm, __shfl_xor(mm, 8));
                mm = fmaxf(mm, __shfl_xor(mm, 16));
                mm = fmaxf(mm, __shfl_xor(mm, 32));
                if (mm > 0.f) {
                    float rr = 1.0f / mm;
                    C2 += log2f(mm);
                    a0 *= rr; a1 *= rr; a2 *= rr; a3 *= rr;
                }
            }
        }
        #pragma unroll
        for (int j=0;j<8;++j) { pbA[j] = pbB[j]; plA[j] = plB[j]; }
    }

    int sA = 2*ylen, sB = sA - 1;
    float vA = __shfl((sA & 2) ? a2 : a0, sA >> 2);
    float vB = __shfl((sB & 2) ? a3 : a1, sB >> 2);
    if (lane == 0) {
        float sum = vA + vB;
        float loss = 0.f;
        if (sum > 0.f) {
            loss = -(log2f(sum) + C2) * 0.6931471805599453f;
            if (!(loss < 5e9f)) loss = 0.f;           // zero_infinity
        }
        atomicAdd(out, loss * (1.0f/B_));
    }
}

// ---------------------------------------------------------------------------
extern "C" void kernel_launch(void* const* d_in, const int* in_sizes, int n_in,
                              void* d_out, int out_size, void* d_ws, size_t ws_size,
                              hipStream_t stream)
{
    const float* eouts = (const float*)d_in[0];
    const float* W     = (const float*)d_in[1];
    const float* bias  = (const float*)d_in[2];
    const int*   ys    = (const int*)d_in[3];
    const int*   elens = (const int*)d_in[4];
    const int*   ylens = (const int*)d_in[5];
    float* out = (float*)d_out;

    char* ws = (char*)d_ws;
    unsigned short* eb = (unsigned short*)ws;                  // 32,768,000 B
    unsigned short* wb = (unsigned short*)(ws + 32768000);     //  2,097,152 B
    float* Srow        = (float*)(ws + 34865152);              //    128,000 B
    float* g           = (float*)(ws + 34993152);              // 13,313,024 B (incl pad)

    prep_kernel<<<17057, 256, 0, stream>>>(eouts, W, eb, wb, Srow, out);
    gemm_lse_kernel<<<dim3(8, 500), 256, 0, stream>>>(eb, wb, bias, Srow);
    gather_kernel<<<dim3(63, 32), 256, 0, stream>>>(eouts, W, bias, ys, Srow, g);
    ctc_dp_kernel<<<B_, 64, 0, stream>>>(g, ys, elens, ylens, out);
}

// Round 2
// 429.319 us; speedup vs baseline: 1.4246x; 1.4246x over previous
//
#include <hip/hip_runtime.h>
#include <hip/hip_bf16.h>

#define B_ 32
#define T_ 1000
#define H_ 512
#define V_ 2048
#define L_ 100
#define M_ (B_*T_)          // 32000 rows
#define GSTRIDE 104         // p_ext row stride (floats): [0]=blank, [2+l]=label l
#define LOG2E 1.4426950408889634f
#define LSE_SHIFT 48.0f

typedef __attribute__((ext_vector_type(8))) short bf16x8;
typedef __attribute__((ext_vector_type(4))) float f32x4;

#define AS_G(p)  ((const __attribute__((address_space(1))) unsigned int*)(p))
#define AS_L(p)  ((__attribute__((address_space(3))) unsigned int*)(p))

__device__ __forceinline__ unsigned short f2bf(float x) {
    unsigned int u; __builtin_memcpy(&u, &x, 4);
    unsigned int r = (u + 0x7fffu + ((u >> 16) & 1u)) >> 16;   // RNE
    return (unsigned short)r;
}

// ---------------------------------------------------------------------------
// Kernel 0: zero out + Srow, convert eouts/W fp32 -> bf16 into ws
// ---------------------------------------------------------------------------
__global__ __launch_bounds__(256) void prep_kernel(
        const float* __restrict__ eouts, const float* __restrict__ W,
        unsigned short* __restrict__ eb, unsigned short* __restrict__ wb,
        float* __restrict__ Srow, float* __restrict__ out)
{
    const int E4 = M_*H_/4;      // 4,096,000
    const int W4 = V_*H_/4;      //   262,144
    const int S4 = M_/4;         //     8,000
    int idx = blockIdx.x*256 + threadIdx.x;
    if (idx == 0) out[0] = 0.f;
    if (idx < E4) {
        float4 v = ((const float4*)eouts)[idx];
        ushort4 o; o.x=f2bf(v.x); o.y=f2bf(v.y); o.z=f2bf(v.z); o.w=f2bf(v.w);
        ((ushort4*)eb)[idx] = o;
    } else if (idx < E4 + W4) {
        int j = idx - E4;
        float4 v = ((const float4*)W)[j];
        ushort4 o; o.x=f2bf(v.x); o.y=f2bf(v.y); o.z=f2bf(v.z); o.w=f2bf(v.w);
        ((ushort4*)wb)[j] = o;
    } else if (idx < E4 + W4 + S4) {
        int j = idx - E4 - W4;
        ((float4*)Srow)[j] = make_float4(0.f,0.f,0.f,0.f);
    }
}

// ---------------------------------------------------------------------------
// Kernel 1: m97-style bf16 MFMA GEMM (logits = eouts @ W^T + b) fused with
// row-wise sum of 2^(z*log2e - 48). 128x128 tile, BK=64, global_load_lds x16.
// 4 waves; wave w: rows (w>>1)*64, cols (w&1)*64, 4x4 16x16x32 frags.
// ---------------------------------------------------------------------------
__global__ __launch_bounds__(256) void gemm_lse_kernel(
        const unsigned short* __restrict__ eb, const unsigned short* __restrict__ wb,
        const float* __restrict__ bias, float* __restrict__ Srow)
{
    __shared__ __align__(16) unsigned short As[128*64];   // unpadded: global_load_lds layout
    __shared__ __align__(16) unsigned short Bs[128*64];
    __shared__ float rs[128];
    const int tid  = threadIdx.x;
    const int w    = tid >> 6;
    const int lane = tid & 63;
    const int m    = lane & 15;
    const int q    = lane >> 4;
    const int wrow = w >> 1;
    const int wcol = w & 1;
    const int nbase = blockIdx.x * 128;
    const int mbase = blockIdx.y * 128;
    if (tid < 128) rs[tid] = 0.f;

    const int rbase = w*32 + (lane >> 3);   // staging row (+j*8)
    const int k8    = (lane & 7) * 8;       // staging k offset (shorts)

    f32x4 acc[4][4];
    #pragma unroll
    for (int i=0;i<4;i++)
        #pragma unroll
        for (int j=0;j<4;j++) acc[i][j] = (f32x4){0.f,0.f,0.f,0.f};

    for (int kc = 0; kc < 8; ++kc) {
        __syncthreads();
        #pragma unroll
        for (int j = 0; j < 4; ++j) {
            const unsigned short* ga = eb + (size_t)(mbase + rbase + j*8)*H_ + kc*64 + k8;
            __builtin_amdgcn_global_load_lds(AS_G(ga), AS_L(As + (w*4+j)*512), 16, 0, 0);
            const unsigned short* gw = wb + (size_t)(nbase + rbase + j*8)*H_ + kc*64 + k8;
            __builtin_amdgcn_global_load_lds(AS_G(gw), AS_L(Bs + (w*4+j)*512), 16, 0, 0);
        }
        __syncthreads();   // compiler drains vmcnt(0) before s_barrier
        #pragma unroll
        for (int kk = 0; kk < 2; ++kk) {
            bf16x8 af[4], bfr[4];
            #pragma unroll
            for (int mi=0;mi<4;mi++)
                af[mi] = *(const bf16x8*)(As + (wrow*64 + mi*16 + m)*64 + kk*32 + q*8);
            #pragma unroll
            for (int ni=0;ni<4;ni++)
                bfr[ni] = *(const bf16x8*)(Bs + (wcol*64 + ni*16 + m)*64 + kk*32 + q*8);
            #pragma unroll
            for (int mi=0;mi<4;mi++)
                #pragma unroll
                for (int ni=0;ni<4;ni++)
                    acc[mi][ni] = __builtin_amdgcn_mfma_f32_16x16x32_bf16(
                        af[mi], bfr[ni], acc[mi][ni], 0, 0, 0);
        }
    }

    // epilogue: exp2 + row reduction. C/D: row = q*4+reg, col = m (per passing R1 kernel)
    float bv[4];
    #pragma unroll
    for (int ni=0;ni<4;ni++) bv[ni] = bias[nbase + wcol*64 + ni*16 + m];
    #pragma unroll
    for (int mi=0;mi<4;mi++) {
        #pragma unroll
        for (int r=0;r<4;r++) {
            float s = 0.f;
            #pragma unroll
            for (int ni=0;ni<4;ni++)
                s += exp2f((acc[mi][ni][r] + bv[ni]) * LOG2E - LSE_SHIFT);
            s += __shfl_xor(s, 1);
            s += __shfl_xor(s, 2);
            s += __shfl_xor(s, 4);
            s += __shfl_xor(s, 8);
            if (m == 0) atomicAdd(&rs[wrow*64 + mi*16 + q*4 + r], s);
        }
    }
    __syncthreads();
    if (tid < 128) atomicAdd(&Srow[mbase + tid], rs[tid]);
}

// ---------------------------------------------------------------------------
// Kernel 2: gather ext-label probs via MFMA. Per (b, t-tile-128) block:
// [128 t] x [128 labels] x [K=512] bf16 GEMM; B-rows gathered from wb by
// vocab id during staging. p = 2^(z2 - (48 + log2(Srow))).
// ---------------------------------------------------------------------------
__global__ __launch_bounds__(256) void gather_mfma_kernel(
        const unsigned short* __restrict__ eb, const unsigned short* __restrict__ wb,
        const float* __restrict__ bias, const int* __restrict__ ys,
        const float* __restrict__ Srow, float* __restrict__ g)
{
    __shared__ __align__(16) unsigned short As[128*64];
    __shared__ __align__(16) unsigned short Bs[128*64];
    __shared__ float ls[128];
    const int tid  = threadIdx.x;
    const int w    = tid >> 6;
    const int lane = tid & 63;
    const int m    = lane & 15;
    const int q    = lane >> 4;
    const int wrow = w >> 1;
    const int wcol = w & 1;
    const int b    = blockIdx.y;
    const int tb   = blockIdx.x * 128;

    if (tid < 128) {
        int t = tb + tid;
        ls[tid] = (t < T_) ? (LSE_SHIFT + log2f(Srow[b*T_ + t])) : 0.f;
    }

    const int rbase = w*32 + (lane >> 3);
    const int k8    = (lane & 7) * 8;

    // per-thread vocab ids for the 4 staged B rows (label index = rbase+j*8)
    int vrow[4];
    #pragma unroll
    for (int j=0;j<4;++j) {
        int labr = rbase + j*8;
        vrow[j] = (labr == 0 || labr > L_) ? 0 : ys[b*L_ + labr - 1];
    }
    // per-lane epilogue columns
    int labc[4]; float bv[4];
    #pragma unroll
    for (int ni=0;ni<4;++ni) {
        int lab = wcol*64 + ni*16 + m;
        labc[ni] = lab;
        int v = (lab == 0 || lab > L_) ? 0 : ys[b*L_ + lab - 1];
        bv[ni] = bias[v];
    }

    f32x4 acc[4][4];
    #pragma unroll
    for (int i=0;i<4;i++)
        #pragma unroll
        for (int j=0;j<4;j++) acc[i][j] = (f32x4){0.f,0.f,0.f,0.f};

    for (int kc = 0; kc < 8; ++kc) {
        __syncthreads();
        #pragma unroll
        for (int j = 0; j < 4; ++j) {
            const unsigned short* ga = eb + (size_t)(b*T_ + tb + rbase + j*8)*H_ + kc*64 + k8;
            __builtin_amdgcn_global_load_lds(AS_G(ga), AS_L(As + (w*4+j)*512), 16, 0, 0);
            const unsigned short* gw = wb + (size_t)vrow[j]*H_ + kc*64 + k8;
            __builtin_amdgcn_global_load_lds(AS_G(gw), AS_L(Bs + (w*4+j)*512), 16, 0, 0);
        }
        __syncthreads();
        #pragma unroll
        for (int kk = 0; kk < 2; ++kk) {
            bf16x8 af[4], bfr[4];
            #pragma unroll
            for (int mi=0;mi<4;mi++)
                af[mi] = *(const bf16x8*)(As + (wrow*64 + mi*16 + m)*64 + kk*32 + q*8);
            #pragma unroll
            for (int ni=0;ni<4;ni++)
                bfr[ni] = *(const bf16x8*)(Bs + (wcol*64 + ni*16 + m)*64 + kk*32 + q*8);
            #pragma unroll
            for (int mi=0;mi<4;mi++)
                #pragma unroll
                for (int ni=0;ni<4;ni++)
                    acc[mi][ni] = __builtin_amdgcn_mfma_f32_16x16x32_bf16(
                        af[mi], bfr[ni], acc[mi][ni], 0, 0, 0);
        }
    }

    #pragma unroll
    for (int mi=0;mi<4;mi++) {
        #pragma unroll
        for (int r=0;r<4;r++) {
            int trow = wrow*64 + mi*16 + q*4 + r;
            int t = tb + trow;
            float l2 = ls[trow];
            #pragma unroll
            for (int ni=0;ni<4;ni++) {
                if (t < T_ && labc[ni] <= L_) {
                    float p = exp2f((acc[mi][ni][r] + bv[ni]) * LOG2E - l2);
                    int off = (labc[ni] == 0) ? 0 : labc[ni] + 1;
                    g[(size_t)(b*T_ + t)*GSTRIDE + off] = p;
                }
            }
        }
    }
}

// ---------------------------------------------------------------------------
// Kernel 3: CTC forward DP, linear domain with periodic max-renorm.
// One wave per batch element; lane owns states 4*lane..4*lane+3.
// ---------------------------------------------------------------------------
__global__ __launch_bounds__(64) void ctc_dp_kernel(
        const float* __restrict__ g, const int* __restrict__ ys,
        const int* __restrict__ elens, const int* __restrict__ ylens,
        float* __restrict__ out)
{
    const int b    = blockIdx.x;
    const int lane = threadIdx.x;
    const float* gb = g + (size_t)b * T_ * GSTRIDE;
    const int ylen = ylens[b];
    const int elen = elens[b];
    const int Sv   = 2*ylen + 1;
    const int s0   = 4*lane;
    const float msk0 = (s0   < Sv) ? 1.f : 0.f;
    const float msk1 = (s0+1 < Sv) ? 1.f : 0.f;
    const float msk2 = (s0+2 < Sv) ? 1.f : 0.f;
    const float msk3 = (s0+3 < Sv) ? 1.f : 0.f;
    const int l0 = 2*lane, l1 = 2*lane + 1;
    int i0 = min(max(l0,1), L_-1);
    int i1 = min(l1, L_-1);
    float sk1 = (l0 >= 1 && l0 < L_ && ys[b*L_+i0] != ys[b*L_+i0-1]) ? 1.f : 0.f;
    float sk3 = (l1 < L_        && ys[b*L_+i1] != ys[b*L_+i1-1]) ? 1.f : 0.f;
    const bool ldok = (lane < 51);

    float pb0  = gb[0];
    float2 pl0 = ldok ? *(const float2*)(gb + 2 + 2*lane) : make_float2(0.f,0.f);
    float a0 = (lane==0) ? pb0   : 0.f;
    float a1 = (lane==0) ? pl0.x : 0.f;
    float a2 = 0.f, a3 = 0.f;
    float C2 = 0.f;   // accumulated log2 of renorm scales (wave-uniform)

    float pbA[8]; float2 plA[8];
    #pragma unroll
    for (int j=0;j<8;++j) {
        int tt = min(1+j, T_-1);
        pbA[j] = gb[tt*GSTRIDE];
        plA[j] = ldok ? *(const float2*)(gb + tt*GSTRIDE + 2 + 2*lane) : make_float2(0.f,0.f);
    }

    for (int tb = 1; tb < elen; tb += 8) {
        float pbB[8]; float2 plB[8];
        #pragma unroll
        for (int j=0;j<8;++j) {                       // prefetch next chunk
            int tt = min(tb+8+j, T_-1);
            pbB[j] = gb[tt*GSTRIDE];
            plB[j] = ldok ? *(const float2*)(gb + tt*GSTRIDE + 2 + 2*lane) : make_float2(0.f,0.f);
        }
        #pragma unroll
        for (int j=0;j<8;++j) {
            int t = tb + j;
            if (t < elen) {                           // wave-uniform guard
                float um1 = __shfl_up(a3, 1);         // prev lane state s0-1
                if (lane == 0) um1 = 0.f;
                float n0 = a0 + um1;
                float n1 = a1 + a0 + sk1*um1;
                float n2 = a2 + a1;
                float n3 = a3 + a2 + sk3*a1;
                a0 = n0 * pbA[j]   * msk0;
                a1 = n1 * plA[j].x * msk1;
                a2 = n2 * pbA[j]   * msk2;
                a3 = n3 * plA[j].y * msk3;
            }
            if ((j & 3) == 3) {                       // renorm every 4 steps
                float mm = fmaxf(fmaxf(a0,a1), fmaxf(a2,a3));
                mm = fmaxf(mm, __shfl_xor(mm, 1));
                mm = fmaxf(mm, __shfl_xor(mm, 2));
                mm = fmaxf(mm, __shfl_xor(mm, 4));
                mm = fmaxf(mm, __shfl_xor(mm, 8));
                mm = fmaxf(mm, __shfl_xor(mm, 16));
                mm = fmaxf(mm, __shfl_xor(mm, 32));
                if (mm > 0.f) {
                    float rr = 1.0f / mm;
                    C2 += log2f(mm);
                    a0 *= rr; a1 *= rr; a2 *= rr; a3 *= rr;
                }
            }
        }
        #pragma unroll
        for (int j=0;j<8;++j) { pbA[j] = pbB[j]; plA[j] = plB[j]; }
    }

    int sA = 2*ylen, sB = sA - 1;
    float vA = __shfl((sA & 2) ? a2 : a0, sA >> 2);
    float vB = __shfl((sB & 2) ? a3 : a1, sB >> 2);
    if (lane == 0) {
        float sum = vA + vB;
        float loss = 0.f;
        if (sum > 0.f) {
            loss = -(log2f(sum) + C2) * 0.6931471805599453f;
            if (!(loss < 5e9f)) loss = 0.f;           // zero_infinity
        }
        atomicAdd(out, loss * (1.0f/B_));
    }
}

// ---------------------------------------------------------------------------
extern "C" void kernel_launch(void* const* d_in, const int* in_sizes, int n_in,
                              void* d_out, int out_size, void* d_ws, size_t ws_size,
                              hipStream_t stream)
{
    const float* eouts = (const float*)d_in[0];
    const float* W     = (const float*)d_in[1];
    const float* bias  = (const float*)d_in[2];
    const int*   ys    = (const int*)d_in[3];
    const int*   elens = (const int*)d_in[4];
    const int*   ylens = (const int*)d_in[5];
    float* out = (float*)d_out;

    char* ws = (char*)d_ws;
    unsigned short* eb = (unsigned short*)ws;                  // 32,768,000 B
    unsigned short* wb = (unsigned short*)(ws + 32768000);     //  2,097,152 B
    float* Srow        = (float*)(ws + 34865152);              //    128,000 B
    float* g           = (float*)(ws + 34993152);              // 13,313,024 B

    prep_kernel<<<17057, 256, 0, stream>>>(eouts, W, eb, wb, Srow, out);
    gemm_lse_kernel<<<dim3(16, 250), 256, 0, stream>>>(eb, wb, bias, Srow);
    gather_mfma_kernel<<<dim3(8, 32), 256, 0, stream>>>(eb, wb, bias, ys, Srow, g);
    ctc_dp_kernel<<<B_, 64, 0, stream>>>(g, ys, elens, ylens, out);
}